// Round 2
// baseline (811.290 us; speedup 1.0000x reference)
//
#include <hip/hip_runtime.h>

#define NN 100000
#define NE 1600000

// folded-weight buffer layout (float offsets)
#define OFF_C0   0
#define OFF_D0   64
#define OFF_WPL0 80
#define OFF_BPL0 6224
#define OFF_C1   6288
#define OFF_D1   6544
#define OFF_WPL1 6608
#define OFF_BPL1 31184
#define WBUF_TOT 31248

// ---------------- weight folding ----------------
__global__ void k_prep(const float* __restrict__ We0, const float* __restrict__ be0,
                       const float* __restrict__ Wpre0, const float* __restrict__ bpre0,
                       const float* __restrict__ Wpost0, const float* __restrict__ bpost0,
                       const float* __restrict__ Wlin0, const float* __restrict__ blin0,
                       const float* __restrict__ We1, const float* __restrict__ be1,
                       const float* __restrict__ Wpre1, const float* __restrict__ bpre1,
                       const float* __restrict__ Wpost1, const float* __restrict__ bpost1,
                       const float* __restrict__ Wlin1, const float* __restrict__ blin1,
                       float* __restrict__ wbuf) {
  int id = blockIdx.x * 256 + threadIdx.x;
  if (id >= WBUF_TOT) return;
  float a = 0.f;
  if (id < OFF_D0) {                       // C0[j,f] = We0 @ Wpre0[32:48]
    int j = id >> 4, f = id & 15;
    for (int t = 0; t < 16; t++) a = fmaf(We0[j*16+t], Wpre0[(32+t)*16+f], a);
  } else if (id < OFF_WPL0) {              // d0 = be0 @ Wpre0[32:48] + bpre0
    int f = id - OFF_D0; a = bpre0[f];
    for (int t = 0; t < 16; t++) a = fmaf(be0[t], Wpre0[(32+t)*16+f], a);
  } else if (id < OFF_BPL0) {              // Wpl0 = Wpost0 @ Wlin0  [96,64]
    int r = id - OFF_WPL0; int k = r >> 6, o = r & 63;
    for (int j = 0; j < 64; j++) a = fmaf(Wpost0[k*64+j], Wlin0[j*64+o], a);
  } else if (id < OFF_C1) {                // bpl0 = bpost0 @ Wlin0 + blin0
    int o = id - OFF_BPL0; a = blin0[o];
    for (int j = 0; j < 64; j++) a = fmaf(bpost0[j], Wlin0[j*64+o], a);
  } else if (id < OFF_D1) {                // C1[j,f] = We1 @ Wpre1[128:192]
    int r = id - OFF_C1; int j = r >> 6, f = r & 63;
    for (int t = 0; t < 64; t++) a = fmaf(We1[j*64+t], Wpre1[(128+t)*64+f], a);
  } else if (id < OFF_WPL1) {              // d1 = be1 @ Wpre1[128:192] + bpre1
    int f = id - OFF_D1; a = bpre1[f];
    for (int t = 0; t < 64; t++) a = fmaf(be1[t], Wpre1[(128+t)*64+f], a);
  } else if (id < OFF_BPL1) {              // Wpl1 = Wpost1 @ Wlin1  [384,64]
    int r = id - OFF_WPL1; int k = r >> 6, o = r & 63;
    for (int j = 0; j < 64; j++) a = fmaf(Wpost1[k*64+j], Wlin1[j*64+o], a);
  } else {                                 // bpl1
    int o = id - OFF_BPL1; a = blin1[o];
    for (int j = 0; j < 64; j++) a = fmaf(bpost1[j], Wlin1[j*64+o], a);
  }
  wbuf[id] = a;
}

// ---------------- CSR build ----------------
__global__ void k_hist(const int* __restrict__ dst, int* __restrict__ cnt) {
  int i = blockIdx.x * 256 + threadIdx.x;
  if (i < NE) atomicAdd(&cnt[dst[i]], 1);
}

__global__ void k_scan1(const int* __restrict__ deg, int* __restrict__ partial,
                        int* __restrict__ bsums) {
  __shared__ int lds[256];
  int i = blockIdx.x * 256 + threadIdx.x;
  int v = (i < NN) ? deg[i] : 0;
  lds[threadIdx.x] = v;
  __syncthreads();
  for (int off = 1; off < 256; off <<= 1) {
    int t = (threadIdx.x >= off) ? lds[threadIdx.x - off] : 0;
    __syncthreads();
    lds[threadIdx.x] += t;
    __syncthreads();
  }
  if (i < NN) partial[i] = lds[threadIdx.x];
  if (threadIdx.x == 255) bsums[blockIdx.x] = lds[255];
}

__global__ void k_scan2(const int* __restrict__ bsums, int* __restrict__ boff, int nb) {
  __shared__ int lds[512];
  int v = ((int)threadIdx.x < nb) ? bsums[threadIdx.x] : 0;
  lds[threadIdx.x] = v;
  __syncthreads();
  for (int off = 1; off < 512; off <<= 1) {
    int t = (threadIdx.x >= off) ? lds[threadIdx.x - off] : 0;
    __syncthreads();
    lds[threadIdx.x] += t;
    __syncthreads();
  }
  if ((int)threadIdx.x < nb) boff[threadIdx.x] = lds[threadIdx.x] - v;  // exclusive
}

__global__ void k_scan3(const int* __restrict__ partial, const int* __restrict__ boff,
                        const int* __restrict__ deg, int* __restrict__ rowptr,
                        int* __restrict__ fill) {
  int i = blockIdx.x * 256 + threadIdx.x;
  if (i < NN) {
    int incl = partial[i] + boff[blockIdx.x];
    rowptr[i + 1] = incl;
    fill[i] = incl - deg[i];
  }
  if (i == 0) rowptr[0] = 0;
}

// phase 1: scatter only a 4B edge-id (min random-write footprint)
__global__ void k_scatter_idx(const int* __restrict__ dst, int* __restrict__ fill,
                              int* __restrict__ perm) {
  int i = blockIdx.x * 256 + threadIdx.x;
  if (i < NE) {
    int pos = atomicAdd(&fill[dst[i]], 1);
    perm[pos] = i;
  }
}

// phase 2: gather-permute — sequential writes, random reads absorbed by L2/L3
__global__ void k_permute(const int* __restrict__ perm, const int* __restrict__ src,
                          const float4* __restrict__ ea, int* __restrict__ col,
                          float4* __restrict__ eap) {
  int i = blockIdx.x * 256 + threadIdx.x;
  if (i < NE) {
    int eid = perm[i];
    col[i] = src[eid];
    eap[i] = ea[eid];
  }
}

// ---------------- layer 0 node pre-projection ----------------
__global__ void k_pre0(const float* __restrict__ x, const float* __restrict__ Wpre0,
                       float* __restrict__ xA0, float* __restrict__ xB0) {
  int t = blockIdx.x * 256 + threadIdx.x;   // NN*32 threads
  int node = t >> 5, k = t & 31;
  int f = k & 15;
  const float* W = Wpre0 + (k < 16 ? 0 : 256);
  const float* xr = x + (size_t)node * 16;
  float a = 0.f;
#pragma unroll
  for (int j = 0; j < 16; j++) a = fmaf(xr[j], W[j*16+f], a);
  if (k < 16) xA0[(size_t)node*16+f] = a; else xB0[(size_t)node*16+f] = a;
}

// ---------------- layer 0 aggregation (wave/node, 4 edge-groups x 16 feats) ----------------
__global__ __launch_bounds__(256) void k_agg0(const float* __restrict__ x,
                                              const float* __restrict__ xA0,
                                              const float* __restrict__ xB0,
                                              const int* __restrict__ rowptr,
                                              const int* __restrict__ col,
                                              const float4* __restrict__ eap,
                                              const float* __restrict__ wbuf,
                                              float* __restrict__ vec96) {
  const int w = threadIdx.x >> 6, lane = threadIdx.x & 63;
  const int g = lane >> 4, f = lane & 15;
  const int node = blockIdx.x * 4 + w;
  const int start = rowptr[node], end = rowptr[node + 1];
  const int cnt = end - start;
  const float c0 = wbuf[OFF_C0 + f],      c1v = wbuf[OFF_C0 + 16 + f];
  const float c2v = wbuf[OFF_C0 + 32 + f], c3v = wbuf[OFF_C0 + 48 + f];
  float s = 0.f, sq = 0.f, mx = -__builtin_inff(), mn = __builtin_inff();
  for (int p = start + g; p < end; p += 4) {
    int si = col[p];
    float4 e0 = eap[p];
    float v = xB0[(size_t)si * 16 + f];
    v = fmaf(e0.x, c0, v); v = fmaf(e0.y, c1v, v);
    v = fmaf(e0.z, c2v, v); v = fmaf(e0.w, c3v, v);
    s += v; sq = fmaf(v, v, sq); mx = fmaxf(mx, v); mn = fminf(mn, v);
  }
  s  += __shfl_xor(s, 16);  s  += __shfl_xor(s, 32);
  sq += __shfl_xor(sq, 16); sq += __shfl_xor(sq, 32);
  mx = fmaxf(mx, __shfl_xor(mx, 16)); mx = fmaxf(mx, __shfl_xor(mx, 32));
  mn = fminf(mn, __shfl_xor(mn, 16)); mn = fminf(mn, __shfl_xor(mn, 32));
  const float c = xA0[(size_t)node * 16 + f] + wbuf[OFF_D0 + f];
  float sum_m, mean_m, mx_m, mn_m, std_m;
  if (cnt > 0) {
    float inv = 1.f / (float)cnt;
    float meanv = s * inv;
    sum_m = fmaf((float)cnt, c, s);
    mean_m = meanv + c;
    mx_m = mx + c; mn_m = mn + c;
    float var = fmaf(-meanv, meanv, sq * inv);
    std_m = sqrtf(fmaxf(var, 0.f) + 1e-5f);
  } else {
    sum_m = 0.f; mean_m = 0.f; mx_m = 0.f; mn_m = 0.f; std_m = sqrtf(1e-5f);
  }
  if (g == 0) {
    float* vr = vec96 + (size_t)node * 96;
    vr[f]      = x[(size_t)node * 16 + f];
    vr[16 + f] = sum_m;
    vr[32 + f] = mean_m;
    vr[48 + f] = mx_m;
    vr[64 + f] = mn_m;
    vr[80 + f] = std_m;
  }
}

// ---------------- layer 1 aggregation (wave/node, 64 lanes = 64 feats) ----------------
__global__ __launch_bounds__(256) void k_agg1(const float* __restrict__ xA1,
                                              const float* __restrict__ xB1,
                                              const int* __restrict__ rowptr,
                                              const int* __restrict__ col,
                                              const float4* __restrict__ eap,
                                              const float* __restrict__ wbuf,
                                              float* __restrict__ agg320) {
  const int w = threadIdx.x >> 6, f = threadIdx.x & 63;
  const int node = blockIdx.x * 4 + w;
  const int start = rowptr[node], end = rowptr[node + 1];
  const int cnt = end - start;
  const float c0 = wbuf[OFF_C1 + f],       c1v = wbuf[OFF_C1 + 64 + f];
  const float c2v = wbuf[OFF_C1 + 128 + f], c3v = wbuf[OFF_C1 + 192 + f];
  float s = 0.f, sq = 0.f, mx = -__builtin_inff(), mn = __builtin_inff();
  int p = start;
  for (; p + 1 < end; p += 2) {
    int s0 = col[p], s1 = col[p + 1];
    float4 e0 = eap[p], e1 = eap[p + 1];
    float v0 = xB1[(size_t)s0 * 64 + f];
    float v1 = xB1[(size_t)s1 * 64 + f];
    v0 = fmaf(e0.x, c0, v0); v0 = fmaf(e0.y, c1v, v0);
    v0 = fmaf(e0.z, c2v, v0); v0 = fmaf(e0.w, c3v, v0);
    v1 = fmaf(e1.x, c0, v1); v1 = fmaf(e1.y, c1v, v1);
    v1 = fmaf(e1.z, c2v, v1); v1 = fmaf(e1.w, c3v, v1);
    s += v0; s += v1;
    sq = fmaf(v0, v0, sq); sq = fmaf(v1, v1, sq);
    mx = fmaxf(mx, fmaxf(v0, v1));
    mn = fminf(mn, fminf(v0, v1));
  }
  if (p < end) {
    int s0 = col[p]; float4 e0 = eap[p];
    float v0 = xB1[(size_t)s0 * 64 + f];
    v0 = fmaf(e0.x, c0, v0); v0 = fmaf(e0.y, c1v, v0);
    v0 = fmaf(e0.z, c2v, v0); v0 = fmaf(e0.w, c3v, v0);
    s += v0; sq = fmaf(v0, v0, sq); mx = fmaxf(mx, v0); mn = fminf(mn, v0);
  }
  const float c = xA1[(size_t)node * 64 + f] + wbuf[OFF_D1 + f];
  float sum_m, mean_m, mx_m, mn_m, std_m;
  if (cnt > 0) {
    float inv = 1.f / (float)cnt;
    float meanv = s * inv;
    sum_m = fmaf((float)cnt, c, s);
    mean_m = meanv + c;
    mx_m = mx + c; mn_m = mn + c;
    float var = fmaf(-meanv, meanv, sq * inv);
    std_m = sqrtf(fmaxf(var, 0.f) + 1e-5f);
  } else {
    sum_m = 0.f; mean_m = 0.f; mx_m = 0.f; mn_m = 0.f; std_m = sqrtf(1e-5f);
  }
  float* ar = agg320 + (size_t)node * 320;
  ar[f] = sum_m; ar[64 + f] = mean_m; ar[128 + f] = mx_m;
  ar[192 + f] = mn_m; ar[256 + f] = std_m;
}

// ---------------- generic tiled fp32 GEMM: C[n,64] = [A1|A2][n,KT] @ B[KT,64] (+bias, relu) ----
template <int KT, int K1, bool RELU>
__global__ __launch_bounds__(256) void k_gemm(const float* __restrict__ A1,
                                              const float* __restrict__ A2,
                                              const float* __restrict__ B,
                                              const float* __restrict__ bias,
                                              float* __restrict__ C, int n) {
  __shared__ float As[32][128];
  __shared__ float Bs[32][64];
  const int tid = threadIdx.x;
  const int tm = tid & 31, tf = tid >> 5;
  const int m0 = blockIdx.x * 128;
  float acc[4][8];
#pragma unroll
  for (int i = 0; i < 4; i++)
#pragma unroll
    for (int j = 0; j < 8; j++) acc[i][j] = 0.f;

  for (int k0 = 0; k0 < KT; k0 += 32) {
    {
      int ml = tid & 127;
      int m = m0 + ml;
      int qh = tid >> 7;
      if (m < n) {
#pragma unroll
        for (int q = 0; q < 4; q++) {
          int kk = qh * 16 + q * 4;
          int kg = k0 + kk;
          const float* srcp; int stride, kl;
          if (kg < K1) { srcp = A1; stride = K1; kl = kg; }
          else { srcp = A2; stride = KT - K1; kl = kg - K1; }
          float4 v = *(const float4*)(srcp + (size_t)m * stride + kl);
          As[kk + 0][ml] = v.x; As[kk + 1][ml] = v.y;
          As[kk + 2][ml] = v.z; As[kk + 3][ml] = v.w;
        }
      } else {
#pragma unroll
        for (int q = 0; q < 4; q++) {
          int kk = qh * 16 + q * 4;
          As[kk][ml] = 0.f; As[kk + 1][ml] = 0.f; As[kk + 2][ml] = 0.f; As[kk + 3][ml] = 0.f;
        }
      }
    }
    {
      int kb = tid >> 3;
      int fb = (tid & 7) * 8;
      const float4* br = (const float4*)(B + (size_t)(k0 + kb) * 64 + fb);
      float4 b0 = br[0], b1 = br[1];
      *(float4*)&Bs[kb][fb] = b0;
      *(float4*)&Bs[kb][fb + 4] = b1;
    }
    __syncthreads();
#pragma unroll 8
    for (int k = 0; k < 32; k++) {
      float av[4], bv[8];
      *(float4*)&av[0] = *(const float4*)&As[k][tm * 4];
      *(float4*)&bv[0] = *(const float4*)&Bs[k][tf * 8];
      *(float4*)&bv[4] = *(const float4*)&Bs[k][tf * 8 + 4];
#pragma unroll
      for (int i = 0; i < 4; i++)
#pragma unroll
        for (int j = 0; j < 8; j++) acc[i][j] = fmaf(av[i], bv[j], acc[i][j]);
    }
    __syncthreads();
  }
  float bb[8];
#pragma unroll
  for (int j = 0; j < 8; j++) bb[j] = bias ? bias[tf * 8 + j] : 0.f;
#pragma unroll
  for (int i = 0; i < 4; i++) {
    int m = m0 + tm * 4 + i;
    if (m < n) {
      float vv[8];
#pragma unroll
      for (int j = 0; j < 8; j++) {
        float v = acc[i][j] + bb[j];
        vv[j] = RELU ? fmaxf(v, 0.f) : v;
      }
      float4* cp = (float4*)(C + (size_t)m * 64 + tf * 8);
      cp[0] = make_float4(vv[0], vv[1], vv[2], vv[3]);
      cp[1] = make_float4(vv[4], vv[5], vv[6], vv[7]);
    }
  }
}

// ---------------- GCN prep: hgs = (h2 @ Wg) * dinv ----------------
__global__ void k_gcnprep(const float* __restrict__ h2, const float* __restrict__ Wg,
                          const int* __restrict__ rowptr,
                          float* __restrict__ hgs, float* __restrict__ dinv) {
  int t = blockIdx.x * 256 + threadIdx.x;   // NN*16 threads
  int node = t >> 4, f = t & 15;
  const float* hr = h2 + (size_t)node * 64;
  float a = 0.f;
#pragma unroll
  for (int j = 0; j < 64; j++) a = fmaf(hr[j], Wg[j * 16 + f], a);
  int dg = rowptr[node + 1] - rowptr[node] + 1;  // +1 self loop
  float dv = 1.0f / sqrtf((float)dg);
  hgs[(size_t)node * 16 + f] = a * dv;
  if (f == 0) dinv[node] = dv;
}

// ---------------- GCN aggregate + MLP head ----------------
__global__ __launch_bounds__(256) void k_head(const float* __restrict__ x,
                                              const float* __restrict__ hgs,
                                              const float* __restrict__ dinv,
                                              const int* __restrict__ rowptr,
                                              const int* __restrict__ col,
                                              const float* __restrict__ bg,
                                              const float* __restrict__ Wh1,
                                              const float* __restrict__ bh1,
                                              const float* __restrict__ Wh2,
                                              const float* __restrict__ bh2,
                                              float* __restrict__ out) {
  __shared__ float zb[4][32];
  __shared__ float o1b[4][10];
  const int w = threadIdx.x >> 6, lane = threadIdx.x & 63;
  const int g = lane >> 4, f = lane & 15;
  const int node = blockIdx.x * 4 + w;
  const int start = rowptr[node], end = rowptr[node + 1];
  float s = 0.f;
  for (int p = start + g; p < end; p += 4) {
    int si = col[p];
    s += hgs[(size_t)si * 16 + f];
  }
  s += __shfl_xor(s, 16); s += __shfl_xor(s, 32);
  if (g == 0) {
    float gout = (s + hgs[(size_t)node * 16 + f]) * dinv[node] + bg[f];
    zb[w][f] = gout;
    zb[w][16 + f] = x[(size_t)node * 16 + f];
  }
  __syncthreads();
  if (lane < 10) {
    float a = bh1[lane];
#pragma unroll
    for (int k = 0; k < 32; k++) a = fmaf(zb[w][k], Wh1[k * 10 + lane], a);
    o1b[w][lane] = fmaxf(a, 0.f);
  }
  __syncthreads();
  if (lane < 10) {
    float a = bh2[lane];
#pragma unroll
    for (int j = 0; j < 10; j++) a = fmaf(o1b[w][j], Wh2[j * 10 + lane], a);
    out[(size_t)node * 10 + lane] = a;
  }
}

// ---------------- launcher ----------------
extern "C" void kernel_launch(void* const* d_in, const int* in_sizes, int n_in,
                              void* d_out, int out_size, void* d_ws, size_t ws_size,
                              hipStream_t stream) {
  const float* x      = (const float*)d_in[0];
  const int*   ei     = (const int*)d_in[1];
  const float* eattr  = (const float*)d_in[2];
  const float* We0    = (const float*)d_in[3];
  const float* be0    = (const float*)d_in[4];
  const float* Wpre0  = (const float*)d_in[5];
  const float* bpre0  = (const float*)d_in[6];
  const float* Wpost0 = (const float*)d_in[7];
  const float* bpost0 = (const float*)d_in[8];
  const float* Wlin0  = (const float*)d_in[9];
  const float* blin0  = (const float*)d_in[10];
  const float* We1    = (const float*)d_in[11];
  const float* be1    = (const float*)d_in[12];
  const float* Wpre1  = (const float*)d_in[13];
  const float* bpre1  = (const float*)d_in[14];
  const float* Wpost1 = (const float*)d_in[15];
  const float* bpost1 = (const float*)d_in[16];
  const float* Wlin1  = (const float*)d_in[17];
  const float* blin1  = (const float*)d_in[18];
  const float* Wg     = (const float*)d_in[19];
  const float* bg     = (const float*)d_in[20];
  const float* Wh1    = (const float*)d_in[21];
  const float* bh1    = (const float*)d_in[22];
  const float* Wh2    = (const float*)d_in[23];
  const float* bh2    = (const float*)d_in[24];
  const int* srcI = ei;
  const int* dstI = ei + NE;
  float* out = (float*)d_out;

  char* base = (char*)d_ws;
  size_t off = 0;
  auto take = [&](size_t bytes) -> char* {
    char* p = base + off;
    off += (bytes + 255) & ~(size_t)255;
    return p;
  };
  int* cnt     = (int*)take((size_t)NN * 4);
  int* rowptr  = (int*)take((size_t)(NN + 1) * 4);
  int* fill    = (int*)take((size_t)NN * 4);
  int* partial = (int*)take((size_t)NN * 4);
  int* bsums   = (int*)take(512 * 4);
  int* boff    = (int*)take(512 * 4);
  int* col     = (int*)take((size_t)NE * 4);
  float4* eap  = (float4*)take((size_t)NE * 16);     // 25.6MB; aliased by h2 later
  float* h2    = (float*)eap;                        // h2 [NN,64] = 25.6MB, alive after eap dies
  float* wbuf  = (float*)take((size_t)WBUF_TOT * 4);
  float* h     = (float*)take((size_t)NN * 64 * 4);
  int*   perm  = (int*)h;                            // perm [NE] = 6.4MB, dead before h written
  float* xA1   = (float*)take((size_t)NN * 64 * 4);
  float* xB1   = (float*)take((size_t)NN * 64 * 4);
  // region Z (128MB): vec96/xA0/xB0 early -> agg320 mid -> hgs/dinv late
  char* Z = take((size_t)NN * 320 * 4);
  float* agg320 = (float*)Z;
  float* vec96  = (float*)Z;
  float* xA0    = (float*)(Z + (size_t)NN * 96 * 4);
  float* xB0    = (float*)(Z + (size_t)NN * 96 * 4 + (size_t)NN * 16 * 4);
  float* hgs    = (float*)Z;
  float* dinv   = (float*)(Z + (size_t)NN * 16 * 4);

  hipMemsetAsync(cnt, 0, (size_t)NN * 4, stream);
  k_prep<<<(WBUF_TOT + 255) / 256, 256, 0, stream>>>(
      We0, be0, Wpre0, bpre0, Wpost0, bpost0, Wlin0, blin0,
      We1, be1, Wpre1, bpre1, Wpost1, bpost1, Wlin1, blin1, wbuf);
  k_hist<<<(NE + 255) / 256, 256, 0, stream>>>(dstI, cnt);
  k_scan1<<<391, 256, 0, stream>>>(cnt, partial, bsums);
  k_scan2<<<1, 512, 0, stream>>>(bsums, boff, 391);
  k_scan3<<<391, 256, 0, stream>>>(partial, boff, cnt, rowptr, fill);
  k_scatter_idx<<<(NE + 255) / 256, 256, 0, stream>>>(dstI, fill, perm);
  k_permute<<<(NE + 255) / 256, 256, 0, stream>>>(perm, srcI, (const float4*)eattr,
                                                  col, eap);
  k_pre0<<<NN * 32 / 256, 256, 0, stream>>>(x, Wpre0, xA0, xB0);
  k_agg0<<<NN / 4, 256, 0, stream>>>(x, xA0, xB0, rowptr, col, eap, wbuf, vec96);
  k_gemm<96, 96, true><<<(NN + 127) / 128, 256, 0, stream>>>(
      vec96, vec96, wbuf + OFF_WPL0, wbuf + OFF_BPL0, h, NN);
  k_gemm<64, 64, false><<<(NN + 127) / 128, 256, 0, stream>>>(
      h, h, Wpre1, nullptr, xA1, NN);
  k_gemm<64, 64, false><<<(NN + 127) / 128, 256, 0, stream>>>(
      h, h, Wpre1 + 64 * 64, nullptr, xB1, NN);
  k_agg1<<<NN / 4, 256, 0, stream>>>(xA1, xB1, rowptr, col, eap, wbuf, agg320);
  k_gemm<384, 64, true><<<(NN + 127) / 128, 256, 0, stream>>>(
      h, agg320, wbuf + OFF_WPL1, wbuf + OFF_BPL1, h2, NN);
  k_gcnprep<<<NN * 16 / 256, 256, 0, stream>>>(h2, Wg, rowptr, hgs, dinv);
  k_head<<<NN / 4, 256, 0, stream>>>(x, hgs, dinv, rowptr, col, bg, Wh1, bh1,
                                     Wh2, bh2, out);
}

// Round 3
// 722.760 us; speedup vs baseline: 1.1225x; 1.1225x over previous
//
#include <hip/hip_runtime.h>

#define NN 100000
#define NE 1600000

// bucketing for two-level CSR sort
#define BSH 9                      // 512 nodes per bucket
#define BSZ (1 << BSH)
#define NB  196                    // ceil(NN / 512)
#define CHUNK 6250                 // NE / 256

// folded-weight buffer layout (float offsets)
#define OFF_C0   0
#define OFF_D0   64
#define OFF_WPL0 80
#define OFF_BPL0 6224
#define OFF_C1   6288
#define OFF_D1   6544
#define OFF_WPL1 6608
#define OFF_BPL1 31184
#define WBUF_TOT 31248

// ---------------- weight folding ----------------
__global__ void k_prep(const float* __restrict__ We0, const float* __restrict__ be0,
                       const float* __restrict__ Wpre0, const float* __restrict__ bpre0,
                       const float* __restrict__ Wpost0, const float* __restrict__ bpost0,
                       const float* __restrict__ Wlin0, const float* __restrict__ blin0,
                       const float* __restrict__ We1, const float* __restrict__ be1,
                       const float* __restrict__ Wpre1, const float* __restrict__ bpre1,
                       const float* __restrict__ Wpost1, const float* __restrict__ bpost1,
                       const float* __restrict__ Wlin1, const float* __restrict__ blin1,
                       float* __restrict__ wbuf) {
  int id = blockIdx.x * 256 + threadIdx.x;
  if (id >= WBUF_TOT) return;
  float a = 0.f;
  if (id < OFF_D0) {
    int j = id >> 4, f = id & 15;
    for (int t = 0; t < 16; t++) a = fmaf(We0[j*16+t], Wpre0[(32+t)*16+f], a);
  } else if (id < OFF_WPL0) {
    int f = id - OFF_D0; a = bpre0[f];
    for (int t = 0; t < 16; t++) a = fmaf(be0[t], Wpre0[(32+t)*16+f], a);
  } else if (id < OFF_BPL0) {
    int r = id - OFF_WPL0; int k = r >> 6, o = r & 63;
    for (int j = 0; j < 64; j++) a = fmaf(Wpost0[k*64+j], Wlin0[j*64+o], a);
  } else if (id < OFF_C1) {
    int o = id - OFF_BPL0; a = blin0[o];
    for (int j = 0; j < 64; j++) a = fmaf(bpost0[j], Wlin0[j*64+o], a);
  } else if (id < OFF_D1) {
    int r = id - OFF_C1; int j = r >> 6, f = r & 63;
    for (int t = 0; t < 64; t++) a = fmaf(We1[j*64+t], Wpre1[(128+t)*64+f], a);
  } else if (id < OFF_WPL1) {
    int f = id - OFF_D1; a = bpre1[f];
    for (int t = 0; t < 64; t++) a = fmaf(be1[t], Wpre1[(128+t)*64+f], a);
  } else if (id < OFF_BPL1) {
    int r = id - OFF_WPL1; int k = r >> 6, o = r & 63;
    for (int j = 0; j < 64; j++) a = fmaf(Wpost1[k*64+j], Wlin1[j*64+o], a);
  } else {
    int o = id - OFF_BPL1; a = blin1[o];
    for (int j = 0; j < 64; j++) a = fmaf(bpost1[j], Wlin1[j*64+o], a);
  }
  wbuf[id] = a;
}

// ---------------- CSR build ----------------
__global__ void k_hist(const int* __restrict__ dst, int* __restrict__ cnt) {
  int i = blockIdx.x * 256 + threadIdx.x;
  if (i < NE) atomicAdd(&cnt[dst[i]], 1);
}

__global__ void k_scan1(const int* __restrict__ deg, int* __restrict__ partial,
                        int* __restrict__ bsums) {
  __shared__ int lds[256];
  int i = blockIdx.x * 256 + threadIdx.x;
  int v = (i < NN) ? deg[i] : 0;
  lds[threadIdx.x] = v;
  __syncthreads();
  for (int off = 1; off < 256; off <<= 1) {
    int t = (threadIdx.x >= off) ? lds[threadIdx.x - off] : 0;
    __syncthreads();
    lds[threadIdx.x] += t;
    __syncthreads();
  }
  if (i < NN) partial[i] = lds[threadIdx.x];
  if (threadIdx.x == 255) bsums[blockIdx.x] = lds[255];
}

__global__ void k_scan2(const int* __restrict__ bsums, int* __restrict__ boff, int nb) {
  __shared__ int lds[512];
  int v = ((int)threadIdx.x < nb) ? bsums[threadIdx.x] : 0;
  lds[threadIdx.x] = v;
  __syncthreads();
  for (int off = 1; off < 512; off <<= 1) {
    int t = (threadIdx.x >= off) ? lds[threadIdx.x - off] : 0;
    __syncthreads();
    lds[threadIdx.x] += t;
    __syncthreads();
  }
  if ((int)threadIdx.x < nb) boff[threadIdx.x] = lds[threadIdx.x] - v;  // exclusive
}

__global__ void k_scan3(const int* __restrict__ partial, const int* __restrict__ boff,
                        const int* __restrict__ deg, int* __restrict__ rowptr,
                        int* __restrict__ fill) {
  int i = blockIdx.x * 256 + threadIdx.x;
  if (i < NN) {
    int incl = partial[i] + boff[blockIdx.x];
    rowptr[i + 1] = incl;
    fill[i] = incl - deg[i];
  }
  if (i == 0) rowptr[0] = 0;
}

// init per-bucket fill = CSR base of bucket (free from rowptr)
__global__ void k_binit(const int* __restrict__ rowptr, int* __restrict__ gfill) {
  int b = threadIdx.x;
  if (b < NB) {
    int n0 = b << BSH;
    gfill[b] = rowptr[n0 > NN ? NN : n0];
  }
}

// pass 1: LDS-binned coarse sort — writes (dst,eid) in per-bucket contiguous runs
__global__ __launch_bounds__(256) void k_bin(const int* __restrict__ dst,
                                             int* __restrict__ gfill,
                                             int2* __restrict__ rec) {
  __shared__ int hcnt[NB];
  __shared__ int hbase[NB];
  const int t = threadIdx.x;
  for (int b = t; b < NB; b += 256) hcnt[b] = 0;
  __syncthreads();
  const int lo = blockIdx.x * CHUNK, hi = lo + CHUNK;
  for (int i = lo + t; i < hi; i += 256)
    atomicAdd(&hcnt[dst[i] >> BSH], 1);
  __syncthreads();
  for (int b = t; b < NB; b += 256) {
    int c = hcnt[b];
    hbase[b] = c > 0 ? atomicAdd(&gfill[b], c) : 0;
    hcnt[b] = 0;  // reuse as running local offset
  }
  __syncthreads();
  for (int i = lo + t; i < hi; i += 256) {
    int d = dst[i];
    int b = d >> BSH;
    int lp = atomicAdd(&hcnt[b], 1);
    rec[hbase[b] + lp] = make_int2(d, i);
  }
}

// pass 2: in-bucket scatter; LDS fill counters give global CSR positions,
// random writes confined to the bucket's ~33KB perm window (L2-resident)
__global__ __launch_bounds__(256) void k_scatter2(const int2* __restrict__ rec,
                                                  const int* __restrict__ rowptr,
                                                  int* __restrict__ perm) {
  __shared__ int lfill[BSZ];
  const int b = blockIdx.x;
  const int n0 = b << BSH;
  const int n1 = (n0 + BSZ < NN) ? n0 + BSZ : NN;
  const int t = threadIdx.x;
  for (int n = n0 + t; n < n1; n += 256) lfill[n - n0] = rowptr[n];
  __syncthreads();
  const int lo = rowptr[n0], hi = rowptr[n1];
  for (int i = lo + t; i < hi; i += 256) {
    int2 r = rec[i];
    int pos = atomicAdd(&lfill[r.x - n0], 1);
    perm[pos] = r.y;
  }
}

// pass 3: gather-permute — sequential writes, random reads absorbed by L2/L3
__global__ void k_permute(const int* __restrict__ perm, const int* __restrict__ src,
                          const float4* __restrict__ ea, int* __restrict__ col,
                          float4* __restrict__ eap) {
  int i = blockIdx.x * 256 + threadIdx.x;
  if (i < NE) {
    int eid = perm[i];
    col[i] = src[eid];
    eap[i] = ea[eid];
  }
}

// ---------------- layer 0 node pre-projection ----------------
__global__ void k_pre0(const float* __restrict__ x, const float* __restrict__ Wpre0,
                       float* __restrict__ xA0, float* __restrict__ xB0) {
  int t = blockIdx.x * 256 + threadIdx.x;   // NN*32 threads
  int node = t >> 5, k = t & 31;
  int f = k & 15;
  const float* W = Wpre0 + (k < 16 ? 0 : 256);
  const float* xr = x + (size_t)node * 16;
  float a = 0.f;
#pragma unroll
  for (int j = 0; j < 16; j++) a = fmaf(xr[j], W[j*16+f], a);
  if (k < 16) xA0[(size_t)node*16+f] = a; else xB0[(size_t)node*16+f] = a;
}

// ---------------- layer 0 aggregation ----------------
__global__ __launch_bounds__(256) void k_agg0(const float* __restrict__ x,
                                              const float* __restrict__ xA0,
                                              const float* __restrict__ xB0,
                                              const int* __restrict__ rowptr,
                                              const int* __restrict__ col,
                                              const float4* __restrict__ eap,
                                              const float* __restrict__ wbuf,
                                              float* __restrict__ vec96) {
  const int w = threadIdx.x >> 6, lane = threadIdx.x & 63;
  const int g = lane >> 4, f = lane & 15;
  const int node = blockIdx.x * 4 + w;
  const int start = rowptr[node], end = rowptr[node + 1];
  const int cnt = end - start;
  const float c0 = wbuf[OFF_C0 + f],      c1v = wbuf[OFF_C0 + 16 + f];
  const float c2v = wbuf[OFF_C0 + 32 + f], c3v = wbuf[OFF_C0 + 48 + f];
  float s = 0.f, sq = 0.f, mx = -__builtin_inff(), mn = __builtin_inff();
  for (int p = start + g; p < end; p += 4) {
    int si = col[p];
    float4 e0 = eap[p];
    float v = xB0[(size_t)si * 16 + f];
    v = fmaf(e0.x, c0, v); v = fmaf(e0.y, c1v, v);
    v = fmaf(e0.z, c2v, v); v = fmaf(e0.w, c3v, v);
    s += v; sq = fmaf(v, v, sq); mx = fmaxf(mx, v); mn = fminf(mn, v);
  }
  s  += __shfl_xor(s, 16);  s  += __shfl_xor(s, 32);
  sq += __shfl_xor(sq, 16); sq += __shfl_xor(sq, 32);
  mx = fmaxf(mx, __shfl_xor(mx, 16)); mx = fmaxf(mx, __shfl_xor(mx, 32));
  mn = fminf(mn, __shfl_xor(mn, 16)); mn = fminf(mn, __shfl_xor(mn, 32));
  const float c = xA0[(size_t)node * 16 + f] + wbuf[OFF_D0 + f];
  float sum_m, mean_m, mx_m, mn_m, std_m;
  if (cnt > 0) {
    float inv = 1.f / (float)cnt;
    float meanv = s * inv;
    sum_m = fmaf((float)cnt, c, s);
    mean_m = meanv + c;
    mx_m = mx + c; mn_m = mn + c;
    float var = fmaf(-meanv, meanv, sq * inv);
    std_m = sqrtf(fmaxf(var, 0.f) + 1e-5f);
  } else {
    sum_m = 0.f; mean_m = 0.f; mx_m = 0.f; mn_m = 0.f; std_m = sqrtf(1e-5f);
  }
  if (g == 0) {
    float* vr = vec96 + (size_t)node * 96;
    vr[f]      = x[(size_t)node * 16 + f];
    vr[16 + f] = sum_m;
    vr[32 + f] = mean_m;
    vr[48 + f] = mx_m;
    vr[64 + f] = mn_m;
    vr[80 + f] = std_m;
  }
}

// ---------------- layer 1 aggregation ----------------
__global__ __launch_bounds__(256) void k_agg1(const float* __restrict__ xA1,
                                              const float* __restrict__ xB1,
                                              const int* __restrict__ rowptr,
                                              const int* __restrict__ col,
                                              const float4* __restrict__ eap,
                                              const float* __restrict__ wbuf,
                                              float* __restrict__ agg320) {
  const int w = threadIdx.x >> 6, f = threadIdx.x & 63;
  const int node = blockIdx.x * 4 + w;
  const int start = rowptr[node], end = rowptr[node + 1];
  const int cnt = end - start;
  const float c0 = wbuf[OFF_C1 + f],       c1v = wbuf[OFF_C1 + 64 + f];
  const float c2v = wbuf[OFF_C1 + 128 + f], c3v = wbuf[OFF_C1 + 192 + f];
  float s = 0.f, sq = 0.f, mx = -__builtin_inff(), mn = __builtin_inff();
  int p = start;
  for (; p + 1 < end; p += 2) {
    int s0 = col[p], s1 = col[p + 1];
    float4 e0 = eap[p], e1 = eap[p + 1];
    float v0 = xB1[(size_t)s0 * 64 + f];
    float v1 = xB1[(size_t)s1 * 64 + f];
    v0 = fmaf(e0.x, c0, v0); v0 = fmaf(e0.y, c1v, v0);
    v0 = fmaf(e0.z, c2v, v0); v0 = fmaf(e0.w, c3v, v0);
    v1 = fmaf(e1.x, c0, v1); v1 = fmaf(e1.y, c1v, v1);
    v1 = fmaf(e1.z, c2v, v1); v1 = fmaf(e1.w, c3v, v1);
    s += v0; s += v1;
    sq = fmaf(v0, v0, sq); sq = fmaf(v1, v1, sq);
    mx = fmaxf(mx, fmaxf(v0, v1));
    mn = fminf(mn, fminf(v0, v1));
  }
  if (p < end) {
    int s0 = col[p]; float4 e0 = eap[p];
    float v0 = xB1[(size_t)s0 * 64 + f];
    v0 = fmaf(e0.x, c0, v0); v0 = fmaf(e0.y, c1v, v0);
    v0 = fmaf(e0.z, c2v, v0); v0 = fmaf(e0.w, c3v, v0);
    s += v0; sq = fmaf(v0, v0, sq); mx = fmaxf(mx, v0); mn = fminf(mn, v0);
  }
  const float c = xA1[(size_t)node * 64 + f] + wbuf[OFF_D1 + f];
  float sum_m, mean_m, mx_m, mn_m, std_m;
  if (cnt > 0) {
    float inv = 1.f / (float)cnt;
    float meanv = s * inv;
    sum_m = fmaf((float)cnt, c, s);
    mean_m = meanv + c;
    mx_m = mx + c; mn_m = mn + c;
    float var = fmaf(-meanv, meanv, sq * inv);
    std_m = sqrtf(fmaxf(var, 0.f) + 1e-5f);
  } else {
    sum_m = 0.f; mean_m = 0.f; mx_m = 0.f; mn_m = 0.f; std_m = sqrtf(1e-5f);
  }
  float* ar = agg320 + (size_t)node * 320;
  ar[f] = sum_m; ar[64 + f] = mean_m; ar[128 + f] = mx_m;
  ar[192 + f] = mn_m; ar[256 + f] = std_m;
}

// ---------------- tiled fp32 GEMM: C[n,64] = [A1|A2][n,KT] @ B[KT,64] ----
template <int KT, int K1, bool RELU>
__global__ __launch_bounds__(256) void k_gemm(const float* __restrict__ A1,
                                              const float* __restrict__ A2,
                                              const float* __restrict__ B,
                                              const float* __restrict__ bias,
                                              float* __restrict__ C, int n) {
  __shared__ float As[32][128];
  __shared__ float Bs[32][64];
  const int tid = threadIdx.x;
  const int tm = tid & 31, tf = tid >> 5;
  const int m0 = blockIdx.x * 128;
  float acc[4][8];
#pragma unroll
  for (int i = 0; i < 4; i++)
#pragma unroll
    for (int j = 0; j < 8; j++) acc[i][j] = 0.f;

  for (int k0 = 0; k0 < KT; k0 += 32) {
    {
      int ml = tid & 127;
      int m = m0 + ml;
      int qh = tid >> 7;
      if (m < n) {
#pragma unroll
        for (int q = 0; q < 4; q++) {
          int kk = qh * 16 + q * 4;
          int kg = k0 + kk;
          const float* srcp; int stride, kl;
          if (kg < K1) { srcp = A1; stride = K1; kl = kg; }
          else { srcp = A2; stride = KT - K1; kl = kg - K1; }
          float4 v = *(const float4*)(srcp + (size_t)m * stride + kl);
          As[kk + 0][ml] = v.x; As[kk + 1][ml] = v.y;
          As[kk + 2][ml] = v.z; As[kk + 3][ml] = v.w;
        }
      } else {
#pragma unroll
        for (int q = 0; q < 4; q++) {
          int kk = qh * 16 + q * 4;
          As[kk][ml] = 0.f; As[kk + 1][ml] = 0.f; As[kk + 2][ml] = 0.f; As[kk + 3][ml] = 0.f;
        }
      }
    }
    {
      int kb = tid >> 3;
      int fb = (tid & 7) * 8;
      const float4* br = (const float4*)(B + (size_t)(k0 + kb) * 64 + fb);
      float4 b0 = br[0], b1 = br[1];
      *(float4*)&Bs[kb][fb] = b0;
      *(float4*)&Bs[kb][fb + 4] = b1;
    }
    __syncthreads();
#pragma unroll 8
    for (int k = 0; k < 32; k++) {
      float av[4], bv[8];
      *(float4*)&av[0] = *(const float4*)&As[k][tm * 4];
      *(float4*)&bv[0] = *(const float4*)&Bs[k][tf * 8];
      *(float4*)&bv[4] = *(const float4*)&Bs[k][tf * 8 + 4];
#pragma unroll
      for (int i = 0; i < 4; i++)
#pragma unroll
        for (int j = 0; j < 8; j++) acc[i][j] = fmaf(av[i], bv[j], acc[i][j]);
    }
    __syncthreads();
  }
  float bb[8];
#pragma unroll
  for (int j = 0; j < 8; j++) bb[j] = bias ? bias[tf * 8 + j] : 0.f;
#pragma unroll
  for (int i = 0; i < 4; i++) {
    int m = m0 + tm * 4 + i;
    if (m < n) {
      float vv[8];
#pragma unroll
      for (int j = 0; j < 8; j++) {
        float v = acc[i][j] + bb[j];
        vv[j] = RELU ? fmaxf(v, 0.f) : v;
      }
      float4* cp = (float4*)(C + (size_t)m * 64 + tf * 8);
      cp[0] = make_float4(vv[0], vv[1], vv[2], vv[3]);
      cp[1] = make_float4(vv[4], vv[5], vv[6], vv[7]);
    }
  }
}

// ---------------- GCN prep: hgs = (h2 @ Wg) * dinv ----------------
__global__ void k_gcnprep(const float* __restrict__ h2, const float* __restrict__ Wg,
                          const int* __restrict__ rowptr,
                          float* __restrict__ hgs, float* __restrict__ dinv) {
  int t = blockIdx.x * 256 + threadIdx.x;   // NN*16 threads
  int node = t >> 4, f = t & 15;
  const float* hr = h2 + (size_t)node * 64;
  float a = 0.f;
#pragma unroll
  for (int j = 0; j < 64; j++) a = fmaf(hr[j], Wg[j * 16 + f], a);
  int dg = rowptr[node + 1] - rowptr[node] + 1;  // +1 self loop
  float dv = 1.0f / sqrtf((float)dg);
  hgs[(size_t)node * 16 + f] = a * dv;
  if (f == 0) dinv[node] = dv;
}

// ---------------- GCN aggregate + MLP head ----------------
__global__ __launch_bounds__(256) void k_head(const float* __restrict__ x,
                                              const float* __restrict__ hgs,
                                              const float* __restrict__ dinv,
                                              const int* __restrict__ rowptr,
                                              const int* __restrict__ col,
                                              const float* __restrict__ bg,
                                              const float* __restrict__ Wh1,
                                              const float* __restrict__ bh1,
                                              const float* __restrict__ Wh2,
                                              const float* __restrict__ bh2,
                                              float* __restrict__ out) {
  __shared__ float zb[4][32];
  __shared__ float o1b[4][10];
  const int w = threadIdx.x >> 6, lane = threadIdx.x & 63;
  const int g = lane >> 4, f = lane & 15;
  const int node = blockIdx.x * 4 + w;
  const int start = rowptr[node], end = rowptr[node + 1];
  float s = 0.f;
  for (int p = start + g; p < end; p += 4) {
    int si = col[p];
    s += hgs[(size_t)si * 16 + f];
  }
  s += __shfl_xor(s, 16); s += __shfl_xor(s, 32);
  if (g == 0) {
    float gout = (s + hgs[(size_t)node * 16 + f]) * dinv[node] + bg[f];
    zb[w][f] = gout;
    zb[w][16 + f] = x[(size_t)node * 16 + f];
  }
  __syncthreads();
  if (lane < 10) {
    float a = bh1[lane];
#pragma unroll
    for (int k = 0; k < 32; k++) a = fmaf(zb[w][k], Wh1[k * 10 + lane], a);
    o1b[w][lane] = fmaxf(a, 0.f);
  }
  __syncthreads();
  if (lane < 10) {
    float a = bh2[lane];
#pragma unroll
    for (int j = 0; j < 10; j++) a = fmaf(o1b[w][j], Wh2[j * 10 + lane], a);
    out[(size_t)node * 10 + lane] = a;
  }
}

// ---------------- launcher ----------------
extern "C" void kernel_launch(void* const* d_in, const int* in_sizes, int n_in,
                              void* d_out, int out_size, void* d_ws, size_t ws_size,
                              hipStream_t stream) {
  const float* x      = (const float*)d_in[0];
  const int*   ei     = (const int*)d_in[1];
  const float* eattr  = (const float*)d_in[2];
  const float* We0    = (const float*)d_in[3];
  const float* be0    = (const float*)d_in[4];
  const float* Wpre0  = (const float*)d_in[5];
  const float* bpre0  = (const float*)d_in[6];
  const float* Wpost0 = (const float*)d_in[7];
  const float* bpost0 = (const float*)d_in[8];
  const float* Wlin0  = (const float*)d_in[9];
  const float* blin0  = (const float*)d_in[10];
  const float* We1    = (const float*)d_in[11];
  const float* be1    = (const float*)d_in[12];
  const float* Wpre1  = (const float*)d_in[13];
  const float* bpre1  = (const float*)d_in[14];
  const float* Wpost1 = (const float*)d_in[15];
  const float* bpost1 = (const float*)d_in[16];
  const float* Wlin1  = (const float*)d_in[17];
  const float* blin1  = (const float*)d_in[18];
  const float* Wg     = (const float*)d_in[19];
  const float* bg     = (const float*)d_in[20];
  const float* Wh1    = (const float*)d_in[21];
  const float* bh1    = (const float*)d_in[22];
  const float* Wh2    = (const float*)d_in[23];
  const float* bh2    = (const float*)d_in[24];
  const int* srcI = ei;
  const int* dstI = ei + NE;
  float* out = (float*)d_out;

  char* base = (char*)d_ws;
  size_t off = 0;
  auto take = [&](size_t bytes) -> char* {
    char* p = base + off;
    off += (bytes + 255) & ~(size_t)255;
    return p;
  };
  int* cnt     = (int*)take((size_t)NN * 4);
  int* rowptr  = (int*)take((size_t)(NN + 1) * 4);
  int* fill    = (int*)take((size_t)NN * 4);
  int* partial = (int*)take((size_t)NN * 4);
  int* bsums   = (int*)take(512 * 4);
  int* boff    = (int*)take(512 * 4);
  int* gfill   = (int*)take(512 * 4);
  int* col     = (int*)take((size_t)NE * 4);
  float4* eap  = (float4*)take((size_t)NE * 16);     // 25.6MB; aliased by h2 later
  float* h2    = (float*)eap;                        // h2 [NN,64], alive after eap dies
  float* wbuf  = (float*)take((size_t)WBUF_TOT * 4);
  float* h     = (float*)take((size_t)NN * 64 * 4);
  int*   perm  = (int*)h;                            // perm [NE] = 6.4MB, dead before h written
  float* xA1   = (float*)take((size_t)NN * 64 * 4);
  int2*  rec   = (int2*)take((size_t)NE * 8);        // 12.8MB; dead before xB1... kept separate
  float* xB1   = (float*)rec;                        // xB1 [NN,64] = 25.6MB > rec? NO: take below
  float* xB1r  = (float*)take((size_t)NN * 64 * 4 - (size_t)NE * 8 > 0 ? (size_t)NN * 64 * 4 - (size_t)NE * 8 : 0);
  (void)xB1r;  // rec(12.8MB) + pad(12.8MB) region doubles as xB1(25.6MB)
  // region Z (128MB): vec96/xA0/xB0 early -> agg320 mid -> hgs/dinv late
  char* Z = take((size_t)NN * 320 * 4);
  float* agg320 = (float*)Z;
  float* vec96  = (float*)Z;
  float* xA0    = (float*)(Z + (size_t)NN * 96 * 4);
  float* xB0    = (float*)(Z + (size_t)NN * 96 * 4 + (size_t)NN * 16 * 4);
  float* hgs    = (float*)Z;
  float* dinv   = (float*)(Z + (size_t)NN * 16 * 4);

  hipMemsetAsync(cnt, 0, (size_t)NN * 4, stream);
  k_prep<<<(WBUF_TOT + 255) / 256, 256, 0, stream>>>(
      We0, be0, Wpre0, bpre0, Wpost0, bpost0, Wlin0, blin0,
      We1, be1, Wpre1, bpre1, Wpost1, bpost1, Wlin1, blin1, wbuf);
  k_hist<<<(NE + 255) / 256, 256, 0, stream>>>(dstI, cnt);
  k_scan1<<<391, 256, 0, stream>>>(cnt, partial, bsums);
  k_scan2<<<1, 512, 0, stream>>>(bsums, boff, 391);
  k_scan3<<<391, 256, 0, stream>>>(partial, boff, cnt, rowptr, fill);
  k_binit<<<1, 256, 0, stream>>>(rowptr, gfill);
  k_bin<<<256, 256, 0, stream>>>(dstI, gfill, rec);
  k_scatter2<<<NB, 256, 0, stream>>>(rec, rowptr, perm);
  k_permute<<<(NE + 255) / 256, 256, 0, stream>>>(perm, srcI, (const float4*)eattr,
                                                  col, eap);
  k_pre0<<<NN * 32 / 256, 256, 0, stream>>>(x, Wpre0, xA0, xB0);
  k_agg0<<<NN / 4, 256, 0, stream>>>(x, xA0, xB0, rowptr, col, eap, wbuf, vec96);
  k_gemm<96, 96, true><<<(NN + 127) / 128, 256, 0, stream>>>(
      vec96, vec96, wbuf + OFF_WPL0, wbuf + OFF_BPL0, h, NN);
  k_gemm<64, 64, false><<<(NN + 127) / 128, 256, 0, stream>>>(
      h, h, Wpre1, nullptr, xA1, NN);
  k_gemm<64, 64, false><<<(NN + 127) / 128, 256, 0, stream>>>(
      h, h, Wpre1 + 64 * 64, nullptr, (float*)rec, NN);   // xB1 overlays rec region
  k_agg1<<<NN / 4, 256, 0, stream>>>(xA1, (float*)rec, rowptr, col, eap, wbuf, agg320);
  k_gemm<384, 64, true><<<(NN + 127) / 128, 256, 0, stream>>>(
      h, agg320, wbuf + OFF_WPL1, wbuf + OFF_BPL1, h2, NN);
  k_gcnprep<<<NN * 16 / 256, 256, 0, stream>>>(h2, Wg, rowptr, hgs, dinv);
  k_head<<<NN / 4, 256, 0, stream>>>(x, hgs, dinv, rowptr, col, bg, Wh1, bh1,
                                     Wh2, bh2, out);
}